// Round 1
// 215.817 us; speedup vs baseline: 1.0685x; 1.0685x over previous
//
#include <hip/hip_runtime.h>

#define NN 50000
#define FIN 128
#define HC 256
#define NH 8
#define NE 800000
#define WROW 136        // padded LDS row (shorts); rows 16B-aligned
#define GEMMB 391       // 391 * 128 rows >= NN
#define NBLK1 3516      // 391 gemm + 3125 fill (3125*256 == NE exactly)
#define OVFCAP 131072

typedef __attribute__((ext_vector_type(8))) short short8;
typedef __attribute__((ext_vector_type(4))) short short4v;
typedef __attribute__((ext_vector_type(4))) float floatx4;

__device__ __forceinline__ float bf2f(unsigned short u) {
    union { unsigned int i; float f; } v; v.i = ((unsigned int)u) << 16; return v.f;
}
__device__ __forceinline__ unsigned short f2bf(float f) {
    union { float f; unsigned int i; } v; v.f = f;
    unsigned int r = v.i + 0x7fffu + ((v.i >> 16) & 1u);
    return (unsigned short)(r >> 16);
}
__device__ __forceinline__ float lrelu(float x) { return x > 0.f ? x : 0.2f * x; }
__device__ __forceinline__ float ldf(const void* p, int f32, long long i) {
    return f32 ? ((const float*)p)[i] : bf2f(((const unsigned short*)p)[i]);
}
__device__ __forceinline__ int lde(const int* ei, int i64, long long i) {
    return i64 ? (int)((const long long*)ei)[i] : ei[i];
}
__device__ __forceinline__ float sel8(const float s[2][4], int t2, int rr) {
    float a0 = t2 ? s[1][0] : s[0][0];
    float a1 = t2 ? s[1][1] : s[0][1];
    float a2 = t2 ? s[1][2] : s[0][2];
    float a3 = t2 ? s[1][3] : s[0][3];
    return (rr == 0) ? a0 : ((rr == 1) ? a1 : ((rr == 2) ? a2 : a3));
}
// bf16 pair unpack from one dword: low short = <<16, high short = mask (no shift)
__device__ __forceinline__ float blo(unsigned int u) {
    union { unsigned int i; float f; } v; v.i = u << 16; return v.f;
}
__device__ __forceinline__ float bhi(unsigned int u) {
    union { unsigned int i; float f; } v; v.i = u & 0xFFFF0000u; return v.f;
}
__device__ __forceinline__ float bperm(int addr, float v) {
    return __uint_as_float((unsigned int)__builtin_amdgcn_ds_bpermute(addr, (int)__float_as_uint(v)));
}

// ---- K1: blocks < GEMMB: MFMA GEMM + attention scores.
//          blocks >= GEMMB: bucket-fill (atomic slot alloc, no scan needed).
__global__ __launch_bounds__(256) void k_front(
        const void* __restrict__ x, const int* __restrict__ ei,
        const void* __restrict__ dpm, const void* __restrict__ W,
        const void* __restrict__ as_, const void* __restrict__ ad_,
        int* __restrict__ flags, unsigned short* __restrict__ h,
        float* __restrict__ a_src, float* __restrict__ a_dst,
        int* __restrict__ cnt, int* __restrict__ ovfcnt,
        unsigned int* __restrict__ bucket, int2* __restrict__ ovf, int cap) {
    __shared__ unsigned short lwt[256 * WROW];   // 69,632 B
    __shared__ int s_bad, s_nz;
    const int tid = threadIdx.x;
    const int b = blockIdx.x;

    // dtype probe (local per block; leading words are L2-hot)
    if (tid == 0) { s_bad = 0; s_nz = 0; }
    __syncthreads();
    {
        unsigned int wv = ((const unsigned int*)dpm)[tid];   // fp32 dp_mask words: 0 or 2.5f
        if (wv != 0u && wv != 0x40200000u) atomicAdd(&s_bad, 1);
        if (((const unsigned int*)ei)[2 * tid + 1] != 0u) atomicAdd(&s_nz, 1);
    }
    __syncthreads();
    const int f32 = (s_bad == 0) ? 1 : 0;
    const int i64 = (s_nz == 0) ? 1 : 0;
    if (b == 0 && tid == 0) { flags[0] = f32; flags[1] = i64; }

    if (b < GEMMB) {
        // ---- stage W^T into LDS: thread tid = output column c; coalesced row reads ----
        {
            if (f32) {
                const float* wp = (const float*)W + tid;
                for (int k = 0; k < FIN; k++) lwt[tid * WROW + k] = f2bf(wp[(long long)k * HC]);
            } else {
                const unsigned short* wp = (const unsigned short*)W + tid;
                for (int k = 0; k < FIN; k++) lwt[tid * WROW + k] = wp[(long long)k * HC];
            }
        }
        __syncthreads();

        const int lane = tid & 63;
        const int wave = tid >> 6;
        const int lrow = lane & 15;
        const int quad = lane >> 4;
        const int row0w = b * 128 + wave * 32;

        short8 a[2][4];
        #pragma unroll
        for (int t = 0; t < 2; t++)
            #pragma unroll
            for (int q = 0; q < 4; q++)
                #pragma unroll
                for (int j = 0; j < 8; j++) a[t][q][j] = 0;

        #pragma unroll
        for (int t = 0; t < 2; t++) {
            int row = row0w + t * 16 + lrow;
            if (row < NN) {
                if (f32) {
                    const float* xp = (const float*)x + (long long)row * FIN + quad * 8;
                    #pragma unroll
                    for (int q = 0; q < 4; q++) {
                        floatx4 u0 = *(const floatx4*)(xp + q * 32);
                        floatx4 u1 = *(const floatx4*)(xp + q * 32 + 4);
                        #pragma unroll
                        for (int j = 0; j < 4; j++) {
                            a[t][q][j]     = (short)f2bf(u0[j]);
                            a[t][q][j + 4] = (short)f2bf(u1[j]);
                        }
                    }
                } else {
                    const unsigned short* xp = (const unsigned short*)x + (long long)row * FIN + quad * 8;
                    #pragma unroll
                    for (int q = 0; q < 4; q++) a[t][q] = *(const short8*)(xp + q * 32);
                }
            }
        }

        float sS[2][4], sD[2][4];
        #pragma unroll 4
        for (int ct = 0; ct < 16; ct++) {
            if ((ct & 1) == 0) {
                #pragma unroll
                for (int t = 0; t < 2; t++)
                    #pragma unroll
                    for (int r = 0; r < 4; r++) { sS[t][r] = 0.f; sD[t][r] = 0.f; }
            }
            floatx4 acc0 = {0.f, 0.f, 0.f, 0.f};
            floatx4 acc1 = {0.f, 0.f, 0.f, 0.f};
            const unsigned short* wp = lwt + (ct * 16 + lrow) * WROW + quad * 8;
            #pragma unroll
            for (int q = 0; q < 4; q++) {
                short8 bb = *(const short8*)(wp + q * 32);
                acc0 = __builtin_amdgcn_mfma_f32_16x16x32_bf16(a[0][q], bb, acc0, 0, 0, 0);
                acc1 = __builtin_amdgcn_mfma_f32_16x16x32_bf16(a[1][q], bb, acc1, 0, 0, 0);
            }
            // C/D: col = lane&15, row = quad*4 + reg
            #pragma unroll
            for (int r = 0; r < 4; r++) {
                int orow = row0w + quad * 4 + r;
                if (orow < NN) h[(long long)orow * HC + ct * 16 + lrow] = f2bf(acc0[r]);
                int orow1 = orow + 16;
                if (orow1 < NN) h[(long long)orow1 * HC + ct * 16 + lrow] = f2bf(acc1[r]);
            }
            float tS = ldf(as_, f32, ct * 16 + lrow);
            float tD = ldf(ad_, f32, ct * 16 + lrow);
            #pragma unroll
            for (int r = 0; r < 4; r++) {
                sS[0][r] += acc0[r] * tS;  sS[1][r] += acc1[r] * tS;
                sD[0][r] += acc0[r] * tD;  sD[1][r] += acc1[r] * tD;
            }
            if (ct & 1) {   // head ct>>1 complete: reduce over 16-lane col group
                #pragma unroll
                for (int m = 1; m <= 8; m <<= 1)
                    #pragma unroll
                    for (int t = 0; t < 2; t++)
                        #pragma unroll
                        for (int r = 0; r < 4; r++) {
                            sS[t][r] += __shfl_xor(sS[t][r], m);
                            sD[t][r] += __shfl_xor(sD[t][r], m);
                        }
                int hd = ct >> 1;
                if (lrow < 8) {
                    int t2 = lrow >> 2, rr = lrow & 3;
                    int row = row0w + t2 * 16 + quad * 4 + rr;
                    if (row < NN) a_src[row * NH + hd] = sel8(sS, t2, rr);
                } else {
                    int lr = lrow - 8;
                    int t2 = lr >> 2, rr = lr & 3;
                    int row = row0w + t2 * 16 + quad * 4 + rr;
                    if (row < NN) a_dst[row * NH + hd] = sel8(sD, t2, rr);
                }
            }
        }
    } else {
        // ---- bucket fill: one edge per thread ----
        int e = (b - GEMMB) * 256 + tid;   // < NE by construction
        int dst = lde(ei, i64, e);
        int src = lde(ei, i64, (long long)NE + e);
        unsigned int msk = 0;
        if (f32) {
            const floatx4* dp = (const floatx4*)((const float*)dpm + (long long)e * 8);
            floatx4 d0 = dp[0], d1 = dp[1];
            #pragma unroll
            for (int j = 0; j < 4; j++) {
                msk |= (d0[j] != 0.f ? 1u : 0u) << j;
                msk |= (d1[j] != 0.f ? 1u : 0u) << (4 + j);
            }
        } else {
            short8 dd = *(const short8*)((const unsigned short*)dpm + (long long)e * 8);
            #pragma unroll
            for (int j = 0; j < 8; j++) msk |= (dd[j] != 0 ? 1u : 0u) << j;
        }
        unsigned int entry = (unsigned int)src | (msk << 16);
        int pos = atomicAdd(&cnt[dst], 1);
        if (pos < cap) bucket[(long long)dst * cap + pos] = entry;
        else {
            int op = atomicAdd(ovfcnt, 1);
            if (op < OVFCAP) ovf[op] = make_int2(dst, (int)entry);
        }
    }
}

// ---- K2: single-pass softmax + aggregation, one wave per node.
//      v2: producer/consumer wave split — lane L computes exp() for exactly one
//      (edge L&7, head L>>3) per 8-edge chunk (8x dedup of score work), dropout
//      bit encoded in the SIGN of the broadcast weight; bucket entries read at
//      wave-uniform addresses (scalarized via readfirstlane) so h-gathers use
//      SGPR-base + lane-offset addressing with zero per-edge VALU address math;
//      no scalar tail loop (last chunk padded with w=0).
__global__ __launch_bounds__(256) void k_aggr(
        const int* __restrict__ cnt, const int* __restrict__ ovfcnt,
        const unsigned int* __restrict__ bucket, const int2* __restrict__ ovf,
        const float* __restrict__ a_src, const float* __restrict__ a_dst,
        const unsigned short* __restrict__ h, const void* __restrict__ dps,
        const int* __restrict__ flags, const void* __restrict__ bs_,
        void* __restrict__ out, int cap) {
    int node = blockIdx.x * 4 + (threadIdx.x >> 6);
    int lane = threadIdx.x & 63;
    if (node >= NN) return;
    const int unode = __builtin_amdgcn_readfirstlane(node);   // wave-uniform -> SGPR
    const int f32 = flags[0];
    int novf = *ovfcnt; novf = novf > OVFCAP ? OVFCAP : novf;
    int mn = cnt[unode]; mn = mn < cap ? mn : cap;
    const unsigned int* __restrict__ bp = bucket + (long long)unode * cap;

    const int hh = lane >> 3;              // head owned by this lane (producer+consumer)
    const int e8 = lane & 7;               // producer's edge slot within chunk
    const int badr = (lane & 56) << 2;     // bpermute byte base of this head group
    const int cb = lane * 4;               // channel base within h-row (shorts)
    const float adst = a_dst[unode * NH + hh];

    float dnp = 0.f;                       // producer-side partial denominator
    float acc0 = 0.f, acc1 = 0.f, acc2 = 0.f, acc3 = 0.f;

    for (int j = 0; j < mn; j += 8) {
        // chunk entries at wave-uniform addresses (scalar-load friendly)
        unsigned int u0 = bp[j + 0], u1 = bp[j + 1], u2 = bp[j + 2], u3 = bp[j + 3],
                     u4 = bp[j + 4], u5 = bp[j + 5], u6 = bp[j + 6], u7 = bp[j + 7];

        // ---- producer: one (edge,head) per lane; clamp keeps loads in-bounds,
        //      padding lanes contribute w = 0.
        int idx = j + e8;
        int idxc = idx < mn ? idx : mn - 1;
        unsigned int ue = bp[idxc];
        int esrc = (int)(ue & 0xFFFFu);
        float al = a_src[esrc * NH + hh] + adst;
        float w = __expf(fmaxf(al, 0.2f * al));
        w = idx < mn ? w : 0.f;
        dnp += w;
        float ws = ((ue >> (16 + hh)) & 1u) ? w : -w;   // sign carries dropout bit

        // ---- consumers: broadcast weights (1 ds_bpermute per edge)
        #define GATW(K) float w##K = bperm(badr + 4 * K, ws);
        GATW(0) GATW(1) GATW(2) GATW(3) GATW(4) GATW(5) GATW(6) GATW(7)
        #undef GATW

        // gather h rows: SGPR base per edge + constant lane offset; batched loads
        #define GATH(K) \
            const unsigned short* hp##K = h + \
                (((long long)(__builtin_amdgcn_readfirstlane((int)u##K) & 0xFFFF)) << 8); \
            uint2 v##K = make_uint2(0u, 0u); \
            if (w##K > 0.f) v##K = *(const uint2*)(hp##K + cb);
        GATH(0) GATH(1) GATH(2) GATH(3) GATH(4) GATH(5) GATH(6) GATH(7)
        #undef GATH

        // unconditional MACs: dropped/padded edges have v == 0 (p*0 == 0)
        #define MACC(K) { float p = w##K * 2.5f; \
            acc0 = fmaf(p, blo(v##K.x), acc0); acc1 = fmaf(p, bhi(v##K.x), acc1); \
            acc2 = fmaf(p, blo(v##K.y), acc2); acc3 = fmaf(p, bhi(v##K.y), acc3); }
        MACC(0) MACC(1) MACC(2) MACC(3) MACC(4) MACC(5) MACC(6) MACC(7)
        #undef MACC
    }

    // reduce producer denominators across the 8 lanes of each head group
    dnp += __shfl_xor(dnp, 1);
    dnp += __shfl_xor(dnp, 2);
    dnp += __shfl_xor(dnp, 4);
    float dn = dnp;

    // overflow sweep (novf ~ 0 in practice; correct for any value)
    for (int i = 0; i < novf; i++) {
        int2 tv = ovf[i];
        if (tv.x == node) {
            unsigned int u = (unsigned int)tv.y;
            int src = (int)(u & 0xFFFFu);
            float w = __expf(lrelu(a_src[src * NH + hh] + adst));
            dn += w;
            if ((u >> (16 + hh)) & 1u) {
                uint2 hv = *(const uint2*)(h + ((long long)src << 8) + cb);
                float p = w * 2.5f;
                acc0 = fmaf(p, blo(hv.x), acc0); acc1 = fmaf(p, bhi(hv.x), acc1);
                acc2 = fmaf(p, blo(hv.y), acc2); acc3 = fmaf(p, bhi(hv.y), acc3);
            }
        }
    }
    { // self-loop
        float wS = __expf(lrelu(a_src[unode * NH + hh] + adst));
        dn += wS;
        float pS = wS * ldf(dps, f32, (long long)unode * NH + hh);
        uint2 hv = *(const uint2*)(h + ((long long)unode << 8) + cb);
        acc0 = fmaf(pS, blo(hv.x), acc0); acc1 = fmaf(pS, bhi(hv.x), acc1);
        acc2 = fmaf(pS, blo(hv.y), acc2); acc3 = fmaf(pS, bhi(hv.y), acc3);
    }
    float inv = 1.0f / dn;
    float b0 = ldf(bs_, f32, cb + 0), b1 = ldf(bs_, f32, cb + 1);
    float b2 = ldf(bs_, f32, cb + 2), b3 = ldf(bs_, f32, cb + 3);
    if (f32) {
        floatx4 o = {acc0 * inv + b0, acc1 * inv + b1, acc2 * inv + b2, acc3 * inv + b3};
        *(floatx4*)((float*)out + (long long)node * HC + cb) = o;
    } else {
        short4v o;
        o[0] = (short)f2bf(acc0 * inv + b0);
        o[1] = (short)f2bf(acc1 * inv + b1);
        o[2] = (short)f2bf(acc2 * inv + b2);
        o[3] = (short)f2bf(acc3 * inv + b3);
        *(short4v*)((unsigned short*)out + (long long)node * HC + cb) = o;
    }
}

extern "C" void kernel_launch(void* const* d_in, const int* in_sizes, int n_in,
                              void* d_out, int out_size, void* d_ws, size_t ws_size,
                              hipStream_t stream) {
    const void* x       = d_in[0];
    const int*  ei      = (const int*)d_in[1];
    const void* dp_mask = d_in[2];
    const void* dp_self = d_in[3];
    const void* W       = d_in[4];
    const void* att_s   = d_in[5];
    const void* att_d   = d_in[6];
    const void* bias    = d_in[7];

    char* w = (char*)d_ws;
    unsigned short* h      = (unsigned short*)(w + 0);             // 25,600,000
    float*          a_src  = (float*)(w + 25600000);               //  1,600,000
    float*          a_dst  = (float*)(w + 27200000);               //  1,600,000
    int*            cnt    = (int*)(w + 28800000);                 //    200,000
    int*            ovfcnt = (int*)(w + 29000000);                 //          4
    int*            flags  = (int*)(w + 29000064);                 //          8
    int2*           ovf    = (int2*)(w + 29000960);                //  1,048,576
    unsigned int*   bucket = (unsigned int*)(w + 30049536);        //  cap*200,000

    // 256 B slack after the bucket region: k_aggr chunk reads may run up to
    // 7 entries past the last node's row (values masked, never dereferenced).
    long long avail = (long long)ws_size - 30049536LL - 256LL;
    int cap = (int)(avail / 200000LL);
    if (cap > 64) cap = 64;
    if (cap < 4) cap = 4;

    // zero cnt + ovfcnt (+flags; flags rewritten by k_front before k_aggr reads)
    hipMemsetAsync(cnt, 0, 200960, stream);
    k_front<<<NBLK1, 256, 0, stream>>>(x, ei, dp_mask, W, att_s, att_d,
                                       flags, h, a_src, a_dst, cnt, ovfcnt, bucket, ovf, cap);
    k_aggr<<<NN / 4, 256, 0, stream>>>(cnt, ovfcnt, bucket, ovf, a_src, a_dst, h,
                                       dp_self, flags, bias, d_out, cap);
}